// Round 7
// baseline (71.467 us; speedup 1.0000x reference)
//
#include <hip/hip_runtime.h>
#include <math.h>

namespace {

constexpr float kAlpha   = 0.75f;
constexpr int   kNumNeg  = 10000;
constexpr int   kNumHard = 100;
constexpr int   kRatio   = 100;
constexpr int   kB       = 8;
constexpr int   kN       = 64 * 128 * 128;     // 1048576
constexpr int   kTpb     = 1024;
constexpr int   kWaves   = kTpb / 64;          // 16
constexpr int   kGatherPerB = 10;              // 10 * 1024 >= 10000
constexpr int   kStreamPerB = 64;
constexpr int   kPerB    = kGatherPerB + kStreamPerB;   // 74
constexpr int   kGatherBlocks = kB * kGatherPerB;       // 80
constexpr int   kGrid    = kGatherBlocks + kB * kStreamPerB;  // 592
constexpr int   kVPer    = (kNumNeg + kTpb - 1) / kTpb; // 10
constexpr unsigned kSentinel = 0xFFFFFFFFu;

// workspace layout (word offsets)
constexpr int oPartials  = 0;       // 8*64*2 floats
constexpr int oBatchLoss = 1024;    // 8 floats
constexpr int oCnt       = 1032;    // 8 u32 per-batch counters
constexpr int oGCnt      = 1040;    // 1 u32 global counter
constexpr int oGvals     = 1536;    // 80000 u32

__device__ __forceinline__ float loss_at(float pred, float target, float mask) {
    float prob = 1.0f / (1.0f + expf(-pred));
    prob = fminf(fmaxf(prob, 1.0e-4f), 1.0f - 1.0e-4f);
    bool pos = (target == 1.0f);
    float alpha_f = pos ? kAlpha : (1.0f - kAlpha);
    float pt = pos ? (1.0f - prob) : prob;
    float focal_w = alpha_f * pt * pt;
    float bce = fmaxf(pred, 0.0f) - pred * target + log1pf(expf(-fabsf(pred)));
    float loss = (mask == 0.0f) ? focal_w * bce : 0.0f;
    if (pos && prob < 0.8f) loss *= 4.0f;
    return loss;
}

// Single kernel. Roles: gather (80 blocks, first), stream (512 blocks).
// Per batch, the LAST of its 74 blocks to finish (counter fetch_add) runs
// the radix select inline. No spin-waits anywhere: deadlock-free under any
// block scheduling; result independent of which block is last.
__global__ void __launch_bounds__(kTpb) fused_kernel(
        const float* __restrict__ pred, const float* __restrict__ target,
        const float* __restrict__ mask, const int* __restrict__ neg_idx,
        unsigned* __restrict__ ws, float* __restrict__ out) {
    const int blk = blockIdx.x;
    const int tid = threadIdx.x;
    const int wave = tid >> 6, lane = tid & 63;
    float* wsf = (float*)ws;

    __shared__ unsigned whist[kWaves][256];           // 16 KB (select)
    __shared__ unsigned hist_total[256], sfx[256];
    __shared__ float sA[kWaves], sB[kWaves];
    __shared__ float sh_np, sh_ps;
    __shared__ unsigned sh_krem, sh_prefix;
    __shared__ int sh_done, sh_last;

    int b;
    if (blk < kGatherBlocks) {
        // ---- gather role ----
        b = blk / kGatherPerB;
        const int sub = blk % kGatherPerB;
        const int j = sub * kTpb + tid;
        if (j < kNumNeg) {
            const size_t base = (size_t)b * kN;
            const int gi = neg_idx[(size_t)b * kNumNeg + j];
            const float tg = target[base + gi];
            unsigned outv;
            if (tg == 1.0f) {
                outv = kSentinel;
            } else {
                float v = loss_at(pred[base + gi], tg, mask[base + gi]);
                outv = __float_as_uint(v);            // v >= 0, finite
            }
            ws[oGvals + b * kNumNeg + j] = outv;
        }
    } else {
        // ---- stream role: 4 independent float4 loads per thread ----
        const int s = blk - kGatherBlocks;
        b = s >> 6;
        const int slice = s & 63;
        const size_t base = (size_t)b * kN;
        const float4* t4 = (const float4*)(target + base);
        const int tb = slice * kTpb + tid;            // [0, 65536)
        constexpr int kStride = kStreamPerB * kTpb;   // 65536; nvec = 4*kStride
        float4 v0 = t4[tb];
        float4 v1 = t4[tb + kStride];
        float4 v2 = t4[tb + 2 * kStride];
        float4 v3 = t4[tb + 3 * kStride];

        float cnt = 0.0f, psum = 0.0f;
        const float4 vv[4] = {v0, v1, v2, v3};
        #pragma unroll
        for (int it = 0; it < 4; ++it) {
            const int i = tb + it * kStride;
            float tvv[4] = {vv[it].x, vv[it].y, vv[it].z, vv[it].w};
            #pragma unroll
            for (int c = 0; c < 4; ++c) {
                if (tvv[c] == 1.0f) {
                    int gi = i * 4 + c;
                    cnt += 1.0f;
                    psum += loss_at(pred[base + gi], 1.0f, mask[base + gi]);
                }
            }
        }
        #pragma unroll
        for (int off = 32; off > 0; off >>= 1) {
            cnt  += __shfl_down(cnt, off);
            psum += __shfl_down(psum, off);
        }
        if (lane == 0) { sA[wave] = cnt; sB[wave] = psum; }
        __syncthreads();
        if (tid == 0) {
            float c = 0.0f, p = 0.0f;
            for (int w = 0; w < kWaves; ++w) { c += sA[w]; p += sB[w]; }
            float* slot = wsf + oPartials + ((size_t)b * kStreamPerB + slice) * 2;
            slot[0] = c; slot[1] = p;
        }
    }

    // ---- publish & elect the per-batch finisher (no spinning) ----
    __syncthreads();   // drains this block's global stores (vmcnt(0))
    if (tid == 0) {
        __threadfence();                              // agent release (wbL2)
        unsigned old = __hip_atomic_fetch_add(&ws[oCnt + b], 1u,
                                              __ATOMIC_ACQ_REL,
                                              __HIP_MEMORY_SCOPE_AGENT);
        sh_last = (old == (unsigned)(kPerB - 1));
    }
    __syncthreads();
    if (!sh_last) return;

    // ================= finisher: radix select for batch b =================
    for (int i = tid; i < kWaves * 256; i += kTpb)
        ((unsigned*)whist)[i] = 0u;
    __syncthreads();

    unsigned vreg[kVPer];
    float mcnt = 0.0f, msum = 0.0f;
    #pragma unroll
    for (int it = 0; it < kVPer; ++it) {
        const int j = tid + it * kTpb;
        unsigned v = kSentinel;
        if (j < kNumNeg) v = ws[oGvals + b * kNumNeg + j];
        vreg[it] = v;
        if (v != kSentinel) {
            mcnt += 1.0f;
            msum += __uint_as_float(v);
            atomicAdd(&whist[wave][v >> 24], 1u);     // v>=0 → bucket <128
        }
    }
    float c = 0.0f, p = 0.0f;
    if (tid < kStreamPerB) {
        const float* slot = wsf + oPartials + ((size_t)b * kStreamPerB + tid) * 2;
        c = slot[0]; p = slot[1];
    }
    #pragma unroll
    for (int off = 32; off > 0; off >>= 1) {
        mcnt += __shfl_down(mcnt, off);
        msum += __shfl_down(msum, off);
        c    += __shfl_down(c, off);
        p    += __shfl_down(p, off);
    }
    __shared__ float r0[kWaves], r1[kWaves], r2[kWaves], r3[kWaves];
    if (lane == 0) { r0[wave] = mcnt; r1[wave] = msum; r2[wave] = c; r3[wave] = p; }
    __syncthreads();
    float my_loss = 0.0f;              // only thread 0's value used
    if (tid == 0) {
        float a0 = 0, a1 = 0, a2 = 0, a3 = 0;
        for (int w = 0; w < kWaves; ++w) { a0 += r0[w]; a1 += r1[w]; a2 += r2[w]; a3 += r3[w]; }
        sh_np = a2; sh_ps = a3;
        const int num_pos = (int)a2;
        const int m = (int)a0;
        const int k = (num_pos > 0) ? min(kRatio * num_pos, kNumNeg) : kNumHard;
        if (k >= m) {
            my_loss = (a3 + a1) / fmaxf(a2, 1.0f);
            sh_done = 1;
        } else {
            sh_done = 0;
            sh_krem = (unsigned)k;
            sh_prefix = 0u;
        }
    }
    __syncthreads();

    if (!sh_done) {
        #pragma unroll
        for (int pass = 0; pass < 4; ++pass) {
            const int shift = 24 - 8 * pass;
            if (pass > 0) {
                for (int i = tid; i < kWaves * 256; i += kTpb)
                    ((unsigned*)whist)[i] = 0u;
                __syncthreads();
                const unsigned pmask = 0xFFFFFFFFu << (shift + 8);
                const unsigned pval = sh_prefix;
                #pragma unroll
                for (int it = 0; it < kVPer; ++it) {
                    unsigned v = vreg[it];
                    if (v != kSentinel && (v & pmask) == pval)
                        atomicAdd(&whist[wave][(v >> shift) & 255u], 1u);
                }
            }
            __syncthreads();
            if (tid < 256) {
                unsigned h = 0;
                #pragma unroll
                for (int w = 0; w < kWaves; ++w) h += whist[w][tid];
                hist_total[tid] = h;
            }
            __syncthreads();
            if (wave == 0) {           // suffix-inclusive sums
                unsigned v0 = hist_total[255 - (4 * lane + 0)];
                unsigned v1 = hist_total[255 - (4 * lane + 1)];
                unsigned v2 = hist_total[255 - (4 * lane + 2)];
                unsigned v3 = hist_total[255 - (4 * lane + 3)];
                unsigned p0 = v0, p1 = p0 + v1, p2 = p1 + v2, p3 = p2 + v3;
                unsigned acc = p3;
                #pragma unroll
                for (int off = 1; off < 64; off <<= 1) {
                    unsigned y = __shfl_up(acc, off);
                    if (lane >= off) acc += y;
                }
                unsigned excl = acc - p3;
                sfx[255 - (4 * lane + 0)] = excl + p0;
                sfx[255 - (4 * lane + 1)] = excl + p1;
                sfx[255 - (4 * lane + 2)] = excl + p2;
                sfx[255 - (4 * lane + 3)] = excl + p3;
            }
            __syncthreads();
            const unsigned krem = sh_krem;            // snapshot before rewrite
            __syncthreads();
            if (tid < 256) {
                unsigned si = sfx[tid];
                bool sel = (si >= krem) && (tid == 255 || sfx[tid + 1] < krem);
                if (sel) {
                    sh_krem = krem - (si - hist_total[tid]);
                    sh_prefix |= (unsigned)tid << shift;
                }
            }
            __syncthreads();
        }

        const unsigned tbits = sh_prefix;
        float gsum = 0.0f;
        #pragma unroll
        for (int it = 0; it < kVPer; ++it) {
            unsigned v = vreg[it];
            if (v != kSentinel && v > tbits) gsum += __uint_as_float(v);
        }
        #pragma unroll
        for (int off = 32; off > 0; off >>= 1) gsum += __shfl_down(gsum, off);
        if (lane == 0) r0[wave] = gsum;
        __syncthreads();
        if (tid == 0) {
            float sum_gt = 0.0f;
            for (int w = 0; w < kWaves; ++w) sum_gt += r0[w];
            const float tval = __uint_as_float(sh_prefix);
            const float neg_sum = sum_gt + (float)sh_krem * tval;
            my_loss = (sh_ps + neg_sum) / fmaxf(sh_np, 1.0f);
        }
    }

    // ---- finalize: 8th finisher computes the mean (fixed order) ----
    if (tid == 0) {
        __hip_atomic_store((float*)&wsf[oBatchLoss + b], my_loss,
                           __ATOMIC_RELEASE, __HIP_MEMORY_SCOPE_AGENT);
        unsigned old = __hip_atomic_fetch_add(&ws[oGCnt], 1u, __ATOMIC_ACQ_REL,
                                              __HIP_MEMORY_SCOPE_AGENT);
        if (old == (unsigned)(kB - 1)) {
            float s = 0.0f;
            for (int i = 0; i < kB; ++i)
                s += __hip_atomic_load((float*)&wsf[oBatchLoss + i],
                                       __ATOMIC_ACQUIRE, __HIP_MEMORY_SCOPE_AGENT);
            out[0] = s / (float)kB;
        }
    }
}

} // namespace

extern "C" void kernel_launch(void* const* d_in, const int* in_sizes, int n_in,
                              void* d_out, int out_size, void* d_ws, size_t ws_size,
                              hipStream_t stream) {
    const float* pred   = (const float*)d_in[0];
    const float* target = (const float*)d_in[1];
    const float* mask   = (const float*)d_in[2];
    const int*   negidx = (const int*)d_in[3];
    unsigned* ws = (unsigned*)d_ws;
    float* out = (float*)d_out;

    // zero the 9 counters (36 B) each call — handshake is re-entrant
    hipMemsetAsync((char*)d_ws + oCnt * 4, 0, (oGCnt - oCnt + 1) * 4, stream);
    fused_kernel<<<dim3(kGrid), dim3(kTpb), 0, stream>>>(pred, target, mask,
                                                         negidx, ws, out);
}

// Round 9
// 29.183 us; speedup vs baseline: 2.4490x; 2.4490x over previous
//
#include <hip/hip_runtime.h>
#include <math.h>

namespace {

constexpr float kAlpha   = 0.75f;
constexpr int   kNumNeg  = 10000;
constexpr int   kNumHard = 100;
constexpr int   kRatio   = 100;
constexpr int   kB       = 8;
constexpr int   kN       = 64 * 128 * 128;   // 1048576
constexpr int   kTpb1    = 256;
constexpr int   kGatherBlocks = (kB * kNumNeg + kTpb1 - 1) / kTpb1;   // 313
constexpr int   kSlices  = 256;                       // stream blocks per batch
constexpr int   kPosBlocks = kB * kSlices;            // 2048
constexpr int   kTpbSel  = 1024;
constexpr int   kWavesSel = kTpbSel / 64;             // 16
constexpr int   kVPerThread = (kNumNeg + kTpbSel - 1) / kTpbSel;  // 10
constexpr unsigned kSentinel = 0xFFFFFFFFu;

__device__ __forceinline__ float loss_at(float pred, float target, float mask) {
    float prob = 1.0f / (1.0f + expf(-pred));
    prob = fminf(fmaxf(prob, 1.0e-4f), 1.0f - 1.0e-4f);
    bool pos = (target == 1.0f);
    float alpha_f = pos ? kAlpha : (1.0f - kAlpha);
    float pt = pos ? (1.0f - prob) : prob;
    float focal_w = alpha_f * pt * pt;
    float bce = fmaxf(pred, 0.0f) - pred * target + log1pf(expf(-fabsf(pred)));
    float loss = (mask == 0.0f) ? focal_w * bce : 0.0f;
    if (pos && prob < 0.8f) loss *= 4.0f;
    return loss;
}

// Stage 1: gather blocks FIRST (random misses start early, overlap under the
// stream), then 2048 stream blocks with 4-deep MLP. Block 0 resets the
// arrival counter (full drain before select ⇒ counter==0 at select start).
__global__ void __launch_bounds__(kTpb1) stage1_kernel(
        const float* __restrict__ pred, const float* __restrict__ target,
        const float* __restrict__ mask, const int* __restrict__ neg_idx,
        float* __restrict__ partials, unsigned* __restrict__ gvals,
        unsigned* __restrict__ counter) {
    const int blk = blockIdx.x;
    if (blk == 0 && threadIdx.x == 0) *counter = 0u;

    if (blk < kGatherBlocks) {
        const int t = blk * kTpb1 + threadIdx.x;
        if (t < kB * kNumNeg) {
            const int b = t / kNumNeg;
            const int j = t - b * kNumNeg;
            const size_t base = (size_t)b * kN;
            const int gi = neg_idx[(size_t)b * kNumNeg + j];
            const float tg = target[base + gi];
            unsigned outv;
            if (tg == 1.0f) {
                outv = kSentinel;
            } else {
                float v = loss_at(pred[base + gi], tg, mask[base + gi]);
                outv = __float_as_uint(v);            // v >= 0, finite
            }
            gvals[(size_t)b * kNumNeg + j] = outv;
        }
        return;
    }

    const int pb = blk - kGatherBlocks;
    const int b = pb >> 8;                            // 256 slices per batch
    const int slice = pb & 255;
    const size_t base = (size_t)b * kN;
    const float4* t4 = (const float4*)(target + base);
    const int tb = slice * kTpb1 + threadIdx.x;       // [0, 65536)
    constexpr int kStride = kSlices * kTpb1;          // 65536; nvec = 4*kStride
    float4 v0 = t4[tb];
    float4 v1 = t4[tb + kStride];
    float4 v2 = t4[tb + 2 * kStride];
    float4 v3 = t4[tb + 3 * kStride];

    float cnt = 0.0f, psum = 0.0f;
    const float4 vv[4] = {v0, v1, v2, v3};
    #pragma unroll
    for (int it = 0; it < 4; ++it) {
        const int i = tb + it * kStride;
        float tvv[4] = {vv[it].x, vv[it].y, vv[it].z, vv[it].w};
        #pragma unroll
        for (int c = 0; c < 4; ++c) {
            if (tvv[c] == 1.0f) {
                int gi = i * 4 + c;
                cnt += 1.0f;
                psum += loss_at(pred[base + gi], 1.0f, mask[base + gi]);
            }
        }
    }
    #pragma unroll
    for (int off = 32; off > 0; off >>= 1) {
        cnt  += __shfl_down(cnt, off);
        psum += __shfl_down(psum, off);
    }
    __shared__ float sc[kTpb1 / 64], sp[kTpb1 / 64];
    const int wave = threadIdx.x / 64, lane = threadIdx.x % 64;
    if (lane == 0) { sc[wave] = cnt; sp[wave] = psum; }
    __syncthreads();
    if (threadIdx.x == 0) {
        float c = 0.0f, p = 0.0f;
        for (int w = 0; w < kTpb1 / 64; ++w) { c += sc[w]; p += sp[w]; }
        float* slot = partials + ((size_t)b * kSlices + slice) * 2;
        slot[0] = c; slot[1] = p;
    }
}

// Stage 2: one block per batch; 4-pass radix select, ping-pong histograms,
// wave-0 in-register suffix scan (2 barriers/pass). TRUE last arriver
// (counter reset by stage1; old == kB-1) computes the final mean.
__global__ void __launch_bounds__(kTpbSel) select_kernel(
        const unsigned* __restrict__ gvals, const float* __restrict__ partials,
        float* __restrict__ batch_loss, unsigned* __restrict__ counter,
        float* __restrict__ out) {
    __shared__ unsigned whist[2][kWavesSel][256];     // 32 KB ping-pong
    __shared__ float r0[kWavesSel], r1[kWavesSel], r2[kWavesSel], r3[kWavesSel];
    __shared__ float red[kWavesSel];
    __shared__ float sh_np, sh_ps;
    __shared__ unsigned sh_krem, sh_prefix;
    __shared__ int sh_done;

    const int b = blockIdx.x;
    const int tid = threadIdx.x;
    const int wave = tid >> 6, lane = tid & 63;

    for (int i = tid; i < 2 * kWavesSel * 256; i += kTpbSel)
        ((unsigned*)whist)[i] = 0u;
    __syncthreads();

    // load candidates into registers; count/sum valid; pass-0 histogram
    unsigned vreg[kVPerThread];
    float mcnt = 0.0f, msum = 0.0f;
    #pragma unroll
    for (int it = 0; it < kVPerThread; ++it) {
        const int j = tid + it * kTpbSel;
        unsigned v = kSentinel;
        if (j < kNumNeg) v = gvals[(size_t)b * kNumNeg + j];
        vreg[it] = v;
        if (v != kSentinel) {
            mcnt += 1.0f;
            msum += __uint_as_float(v);
            atomicAdd(&whist[0][wave][v >> 24], 1u);  // v>=0 → bucket <128
        }
    }
    float c = 0.0f, p = 0.0f;
    if (tid < kSlices) {
        const float* slot = partials + ((size_t)b * kSlices + tid) * 2;
        c = slot[0]; p = slot[1];
    }
    #pragma unroll
    for (int off = 32; off > 0; off >>= 1) {
        mcnt += __shfl_down(mcnt, off);
        msum += __shfl_down(msum, off);
        c    += __shfl_down(c, off);
        p    += __shfl_down(p, off);
    }
    if (lane == 0) { r0[wave] = mcnt; r1[wave] = msum; r2[wave] = c; r3[wave] = p; }
    __syncthreads();
    float my_loss = 0.0f;              // only thread 0's value is used
    if (tid == 0) {
        float a0 = 0, a1 = 0, a2 = 0, a3 = 0;
        for (int w = 0; w < kWavesSel; ++w) { a0 += r0[w]; a1 += r1[w]; a2 += r2[w]; a3 += r3[w]; }
        sh_np = a2; sh_ps = a3;
        const int num_pos = (int)a2;
        const int m = (int)a0;
        const int k = (num_pos > 0) ? min(kRatio * num_pos, kNumNeg) : kNumHard;
        if (k >= m) {
            my_loss = (a3 + a1) / fmaxf(a2, 1.0f);
            sh_done = 1;
        } else {
            sh_done = 0;
            sh_krem = (unsigned)k;
            sh_prefix = 0u;
        }
    }
    __syncthreads();

    if (!sh_done) {
        #pragma unroll
        for (int pass = 0; pass < 4; ++pass) {
            const int shift = 24 - 8 * pass;
            if (pass > 0) {
                // whist[pass&1] was zeroed during the previous pass's scan
                const unsigned pmask = 0xFFFFFFFFu << (shift + 8);
                const unsigned pval = sh_prefix;
                #pragma unroll
                for (int it = 0; it < kVPerThread; ++it) {
                    unsigned v = vreg[it];
                    if (v != kSentinel && (v & pmask) == pval)
                        atomicAdd(&whist[pass & 1][wave][(v >> shift) & 255u], 1u);
                }
                __syncthreads();
            }
            if (wave == 0) {
                // reduce 16 private hists + suffix scan + select, in registers
                const int binbase = 252 - 4 * lane;
                unsigned v0 = 0, v1 = 0, v2 = 0, v3 = 0;
                #pragma unroll
                for (int w = 0; w < kWavesSel; ++w) {
                    uint4 q = *(const uint4*)&whist[pass & 1][w][binbase];
                    v0 += q.x; v1 += q.y; v2 += q.z; v3 += q.w;
                }
                // descending bins: d0=binbase+3 ... d3=binbase+0
                const unsigned d0 = v3, d1 = v2, d2 = v1, d3 = v0;
                const unsigned p0 = d0, p1 = p0 + d1, p2 = p1 + d2, p3 = p2 + d3;
                unsigned acc = p3;
                #pragma unroll
                for (int off = 1; off < 64; off <<= 1) {
                    unsigned y = __shfl_up(acc, off);
                    if (lane >= off) acc += y;
                }
                const unsigned excl = acc - p3;       // sfx of bin binbase+4
                const unsigned krem = sh_krem;
                const unsigned s0 = excl + p0, s1 = excl + p1,
                               s2 = excl + p2, s3 = excl + p3;
                // crossing bin: sfx >= krem && sfx(bin+1) < krem  (unique)
                if (s0 >= krem && excl < krem) {
                    sh_krem = krem - (s0 - d0);
                    sh_prefix |= (unsigned)(binbase + 3) << shift;
                } else if (s1 >= krem && s0 < krem) {
                    sh_krem = krem - (s1 - d1);
                    sh_prefix |= (unsigned)(binbase + 2) << shift;
                } else if (s2 >= krem && s1 < krem) {
                    sh_krem = krem - (s2 - d2);
                    sh_prefix |= (unsigned)(binbase + 1) << shift;
                } else if (s3 >= krem && s2 < krem) {
                    sh_krem = krem - (s3 - d3);
                    sh_prefix |= (unsigned)(binbase + 0) << shift;
                }
            } else {
                // waves 1-15: zero the OTHER buffer for the next pass
                for (int i = tid - 64; i < kWavesSel * 256; i += kTpbSel - 64)
                    ((unsigned*)whist[(pass + 1) & 1])[i] = 0u;
            }
            __syncthreads();
        }

        const unsigned tbits = sh_prefix;
        float gsum = 0.0f;
        #pragma unroll
        for (int it = 0; it < kVPerThread; ++it) {
            unsigned v = vreg[it];
            if (v != kSentinel && v > tbits) gsum += __uint_as_float(v);
        }
        #pragma unroll
        for (int off = 32; off > 0; off >>= 1) gsum += __shfl_down(gsum, off);
        if (lane == 0) red[wave] = gsum;
        __syncthreads();
        if (tid == 0) {
            float sum_gt = 0.0f;
            for (int w = 0; w < kWavesSel; ++w) sum_gt += red[w];
            const float tval = __uint_as_float(tbits);
            const float neg_sum = sum_gt + (float)sh_krem * tval;
            my_loss = (sh_ps + neg_sum) / fmaxf(sh_np, 1.0f);
        }
    }

    // fused finalize: counter==0 at select start (stage1 reset + full drain),
    // so old == kB-1 identifies the TRUE last arriver; the 7 prior
    // release-stores are visible via the counter's release sequence.
    if (tid == 0) {
        __hip_atomic_store(&batch_loss[b], my_loss, __ATOMIC_RELEASE,
                           __HIP_MEMORY_SCOPE_AGENT);
        unsigned old = __hip_atomic_fetch_add(counter, 1u, __ATOMIC_ACQ_REL,
                                              __HIP_MEMORY_SCOPE_AGENT);
        if (old == (unsigned)(kB - 1)) {
            float s = 0.0f;
            for (int i = 0; i < kB; ++i)
                s += __hip_atomic_load(&batch_loss[i], __ATOMIC_ACQUIRE,
                                       __HIP_MEMORY_SCOPE_AGENT);
            out[0] = s / (float)kB;
        }
    }
}

} // namespace

extern "C" void kernel_launch(void* const* d_in, const int* in_sizes, int n_in,
                              void* d_out, int out_size, void* d_ws, size_t ws_size,
                              hipStream_t stream) {
    const float* pred   = (const float*)d_in[0];
    const float* target = (const float*)d_in[1];
    const float* mask   = (const float*)d_in[2];
    const int*   negidx = (const int*)d_in[3];
    float* ws = (float*)d_ws;
    float*    partials   = ws;                         // 2048*2 floats
    float*    batch_loss = ws + 4096;                  // 8 floats
    unsigned* counter    = (unsigned*)(ws + 4104);     // 1 uint
    unsigned* gvals      = (unsigned*)(ws + 4112);     // 80000 uints
    float* out = (float*)d_out;

    stage1_kernel<<<dim3(kGatherBlocks + kPosBlocks), dim3(kTpb1), 0, stream>>>(
        pred, target, mask, negidx, partials, gvals, counter);
    select_kernel<<<dim3(kB), dim3(kTpbSel), 0, stream>>>(
        gvals, partials, batch_loss, counter, out);
}

// Round 10
// 28.703 us; speedup vs baseline: 2.4899x; 1.0167x over previous
//
#include <hip/hip_runtime.h>
#include <math.h>

namespace {

constexpr float kAlpha   = 0.75f;
constexpr int   kNumNeg  = 10000;
constexpr int   kNumHard = 100;
constexpr int   kRatio   = 100;
constexpr int   kB       = 8;
constexpr int   kN       = 64 * 128 * 128;   // 1048576
constexpr int   kTpb1    = 256;
constexpr int   kSlices  = 256;                       // stream blocks per batch
constexpr int   kPosBlocks = kB * kSlices;            // 2048
constexpr int   kGatherBlocksReal = (kB * kNumNeg + kTpb1 - 1) / kTpb1;  // 313
constexpr int   kGrid1   = 2560;                      // 2048 stream + 512 gather slots
constexpr int   kTpbSel  = 1024;
constexpr int   kWavesSel = kTpbSel / 64;             // 16
constexpr int   kVPerThread = (kNumNeg + kTpbSel - 1) / kTpbSel;  // 10
constexpr unsigned kSentinel = 0xFFFFFFFFu;

__device__ __forceinline__ float loss_at(float pred, float target, float mask) {
    float prob = 1.0f / (1.0f + expf(-pred));
    prob = fminf(fmaxf(prob, 1.0e-4f), 1.0f - 1.0e-4f);
    bool pos = (target == 1.0f);
    float alpha_f = pos ? kAlpha : (1.0f - kAlpha);
    float pt = pos ? (1.0f - prob) : prob;
    float focal_w = alpha_f * pt * pt;
    float bce = fmaxf(pred, 0.0f) - pred * target + log1pf(expf(-fabsf(pred)));
    float loss = (mask == 0.0f) ? focal_w * bce : 0.0f;
    if (pos && prob < 0.8f) loss *= 4.0f;
    return loss;
}

// Stage 1: gather blocks INTERLEAVED among stream blocks (every 5th slot) so
// each CU holds ~1 latency-bound gather block + ~7 BW-bound stream blocks —
// the 3-deep random-miss chains hide under the stream for the whole phase
// instead of monopolizing all CUs at dispatch start (round-9 lesson).
__global__ void __launch_bounds__(kTpb1) stage1_kernel(
        const float* __restrict__ pred, const float* __restrict__ target,
        const float* __restrict__ mask, const int* __restrict__ neg_idx,
        float* __restrict__ partials, unsigned* __restrict__ gvals,
        unsigned* __restrict__ counter) {
    const int blk = blockIdx.x;
    if (blk == 0 && threadIdx.x == 0) *counter = 0u;

    if (blk % 5 == 2) {
        // ---- gather slot ----
        const int g = blk / 5;                        // 0..511; real: <313
        if (g >= kGatherBlocksReal) return;
        const int t = g * kTpb1 + threadIdx.x;
        if (t < kB * kNumNeg) {
            const int b = t / kNumNeg;
            const int j = t - b * kNumNeg;
            const size_t base = (size_t)b * kN;
            const int gi = neg_idx[(size_t)b * kNumNeg + j];
            const float tg = target[base + gi];
            unsigned outv;
            if (tg == 1.0f) {
                outv = kSentinel;
            } else {
                float v = loss_at(pred[base + gi], tg, mask[base + gi]);
                outv = __float_as_uint(v);            // v >= 0, finite
            }
            gvals[(size_t)b * kNumNeg + j] = outv;
        }
        return;
    }

    // ---- stream slot: sid covers 0..2047 exactly once ----
    const int sid = blk - (blk + 2) / 5;
    const int b = sid >> 8;                           // 256 slices per batch
    const int slice = sid & 255;
    const size_t base = (size_t)b * kN;
    const float4* t4 = (const float4*)(target + base);
    const int tb = slice * kTpb1 + threadIdx.x;       // [0, 65536)
    constexpr int kStride = kSlices * kTpb1;          // 65536; nvec = 4*kStride
    float4 v0 = t4[tb];
    float4 v1 = t4[tb + kStride];
    float4 v2 = t4[tb + 2 * kStride];
    float4 v3 = t4[tb + 3 * kStride];

    float cnt = 0.0f, psum = 0.0f;
    const float4 vv[4] = {v0, v1, v2, v3};
    #pragma unroll
    for (int it = 0; it < 4; ++it) {
        const int i = tb + it * kStride;
        float tvv[4] = {vv[it].x, vv[it].y, vv[it].z, vv[it].w};
        #pragma unroll
        for (int c = 0; c < 4; ++c) {
            if (tvv[c] == 1.0f) {
                int gi = i * 4 + c;
                cnt += 1.0f;
                psum += loss_at(pred[base + gi], 1.0f, mask[base + gi]);
            }
        }
    }
    #pragma unroll
    for (int off = 32; off > 0; off >>= 1) {
        cnt  += __shfl_down(cnt, off);
        psum += __shfl_down(psum, off);
    }
    __shared__ float sc[kTpb1 / 64], sp[kTpb1 / 64];
    const int wave = threadIdx.x / 64, lane = threadIdx.x % 64;
    if (lane == 0) { sc[wave] = cnt; sp[wave] = psum; }
    __syncthreads();
    if (threadIdx.x == 0) {
        float c = 0.0f, p = 0.0f;
        for (int w = 0; w < kTpb1 / 64; ++w) { c += sc[w]; p += sp[w]; }
        float* slot = partials + ((size_t)b * kSlices + slice) * 2;
        slot[0] = c; slot[1] = p;
    }
}

// Stage 2: unchanged from round 9 (passed). One block per batch; 4-pass radix
// select, ping-pong histograms, wave-0 in-register suffix scan; TRUE last
// arriver (counter reset by stage1) computes the final mean.
__global__ void __launch_bounds__(kTpbSel) select_kernel(
        const unsigned* __restrict__ gvals, const float* __restrict__ partials,
        float* __restrict__ batch_loss, unsigned* __restrict__ counter,
        float* __restrict__ out) {
    __shared__ unsigned whist[2][kWavesSel][256];     // 32 KB ping-pong
    __shared__ float r0[kWavesSel], r1[kWavesSel], r2[kWavesSel], r3[kWavesSel];
    __shared__ float red[kWavesSel];
    __shared__ float sh_np, sh_ps;
    __shared__ unsigned sh_krem, sh_prefix;
    __shared__ int sh_done;

    const int b = blockIdx.x;
    const int tid = threadIdx.x;
    const int wave = tid >> 6, lane = tid & 63;

    for (int i = tid; i < 2 * kWavesSel * 256; i += kTpbSel)
        ((unsigned*)whist)[i] = 0u;
    __syncthreads();

    unsigned vreg[kVPerThread];
    float mcnt = 0.0f, msum = 0.0f;
    #pragma unroll
    for (int it = 0; it < kVPerThread; ++it) {
        const int j = tid + it * kTpbSel;
        unsigned v = kSentinel;
        if (j < kNumNeg) v = gvals[(size_t)b * kNumNeg + j];
        vreg[it] = v;
        if (v != kSentinel) {
            mcnt += 1.0f;
            msum += __uint_as_float(v);
            atomicAdd(&whist[0][wave][v >> 24], 1u);  // v>=0 → bucket <128
        }
    }
    float c = 0.0f, p = 0.0f;
    if (tid < kSlices) {
        const float* slot = partials + ((size_t)b * kSlices + tid) * 2;
        c = slot[0]; p = slot[1];
    }
    #pragma unroll
    for (int off = 32; off > 0; off >>= 1) {
        mcnt += __shfl_down(mcnt, off);
        msum += __shfl_down(msum, off);
        c    += __shfl_down(c, off);
        p    += __shfl_down(p, off);
    }
    if (lane == 0) { r0[wave] = mcnt; r1[wave] = msum; r2[wave] = c; r3[wave] = p; }
    __syncthreads();
    float my_loss = 0.0f;              // only thread 0's value is used
    if (tid == 0) {
        float a0 = 0, a1 = 0, a2 = 0, a3 = 0;
        for (int w = 0; w < kWavesSel; ++w) { a0 += r0[w]; a1 += r1[w]; a2 += r2[w]; a3 += r3[w]; }
        sh_np = a2; sh_ps = a3;
        const int num_pos = (int)a2;
        const int m = (int)a0;
        const int k = (num_pos > 0) ? min(kRatio * num_pos, kNumNeg) : kNumHard;
        if (k >= m) {
            my_loss = (a3 + a1) / fmaxf(a2, 1.0f);
            sh_done = 1;
        } else {
            sh_done = 0;
            sh_krem = (unsigned)k;
            sh_prefix = 0u;
        }
    }
    __syncthreads();

    if (!sh_done) {
        #pragma unroll
        for (int pass = 0; pass < 4; ++pass) {
            const int shift = 24 - 8 * pass;
            if (pass > 0) {
                const unsigned pmask = 0xFFFFFFFFu << (shift + 8);
                const unsigned pval = sh_prefix;
                #pragma unroll
                for (int it = 0; it < kVPerThread; ++it) {
                    unsigned v = vreg[it];
                    if (v != kSentinel && (v & pmask) == pval)
                        atomicAdd(&whist[pass & 1][wave][(v >> shift) & 255u], 1u);
                }
                __syncthreads();
            }
            if (wave == 0) {
                const int binbase = 252 - 4 * lane;
                unsigned v0 = 0, v1 = 0, v2 = 0, v3 = 0;
                #pragma unroll
                for (int w = 0; w < kWavesSel; ++w) {
                    uint4 q = *(const uint4*)&whist[pass & 1][w][binbase];
                    v0 += q.x; v1 += q.y; v2 += q.z; v3 += q.w;
                }
                const unsigned d0 = v3, d1 = v2, d2 = v1, d3 = v0;
                const unsigned p0 = d0, p1 = p0 + d1, p2 = p1 + d2, p3 = p2 + d3;
                unsigned acc = p3;
                #pragma unroll
                for (int off = 1; off < 64; off <<= 1) {
                    unsigned y = __shfl_up(acc, off);
                    if (lane >= off) acc += y;
                }
                const unsigned excl = acc - p3;       // sfx of bin binbase+4
                const unsigned krem = sh_krem;
                const unsigned s0 = excl + p0, s1 = excl + p1,
                               s2 = excl + p2, s3 = excl + p3;
                if (s0 >= krem && excl < krem) {
                    sh_krem = krem - (s0 - d0);
                    sh_prefix |= (unsigned)(binbase + 3) << shift;
                } else if (s1 >= krem && s0 < krem) {
                    sh_krem = krem - (s1 - d1);
                    sh_prefix |= (unsigned)(binbase + 2) << shift;
                } else if (s2 >= krem && s1 < krem) {
                    sh_krem = krem - (s2 - d2);
                    sh_prefix |= (unsigned)(binbase + 1) << shift;
                } else if (s3 >= krem && s2 < krem) {
                    sh_krem = krem - (s3 - d3);
                    sh_prefix |= (unsigned)(binbase + 0) << shift;
                }
            } else {
                for (int i = tid - 64; i < kWavesSel * 256; i += kTpbSel - 64)
                    ((unsigned*)whist[(pass + 1) & 1])[i] = 0u;
            }
            __syncthreads();
        }

        const unsigned tbits = sh_prefix;
        float gsum = 0.0f;
        #pragma unroll
        for (int it = 0; it < kVPerThread; ++it) {
            unsigned v = vreg[it];
            if (v != kSentinel && v > tbits) gsum += __uint_as_float(v);
        }
        #pragma unroll
        for (int off = 32; off > 0; off >>= 1) gsum += __shfl_down(gsum, off);
        if (lane == 0) red[wave] = gsum;
        __syncthreads();
        if (tid == 0) {
            float sum_gt = 0.0f;
            for (int w = 0; w < kWavesSel; ++w) sum_gt += red[w];
            const float tval = __uint_as_float(tbits);
            const float neg_sum = sum_gt + (float)sh_krem * tval;
            my_loss = (sh_ps + neg_sum) / fmaxf(sh_np, 1.0f);
        }
    }

    if (tid == 0) {
        __hip_atomic_store(&batch_loss[b], my_loss, __ATOMIC_RELEASE,
                           __HIP_MEMORY_SCOPE_AGENT);
        unsigned old = __hip_atomic_fetch_add(counter, 1u, __ATOMIC_ACQ_REL,
                                              __HIP_MEMORY_SCOPE_AGENT);
        if (old == (unsigned)(kB - 1)) {
            float s = 0.0f;
            for (int i = 0; i < kB; ++i)
                s += __hip_atomic_load(&batch_loss[i], __ATOMIC_ACQUIRE,
                                       __HIP_MEMORY_SCOPE_AGENT);
            out[0] = s / (float)kB;
        }
    }
}

} // namespace

extern "C" void kernel_launch(void* const* d_in, const int* in_sizes, int n_in,
                              void* d_out, int out_size, void* d_ws, size_t ws_size,
                              hipStream_t stream) {
    const float* pred   = (const float*)d_in[0];
    const float* target = (const float*)d_in[1];
    const float* mask   = (const float*)d_in[2];
    const int*   negidx = (const int*)d_in[3];
    float* ws = (float*)d_ws;
    float*    partials   = ws;                         // 2048*2 floats
    float*    batch_loss = ws + 4096;                  // 8 floats
    unsigned* counter    = (unsigned*)(ws + 4104);     // 1 uint
    unsigned* gvals      = (unsigned*)(ws + 4112);     // 80000 uints
    float* out = (float*)d_out;

    stage1_kernel<<<dim3(kGrid1), dim3(kTpb1), 0, stream>>>(
        pred, target, mask, negidx, partials, gvals, counter);
    select_kernel<<<dim3(kB), dim3(kTpbSel), 0, stream>>>(
        gvals, partials, batch_loss, counter, out);
}